// Round 5
// baseline (3857.781 us; speedup 1.0000x reference)
//
#include <hip/hip_runtime.h>
#include <cstdint>

#define T_STEPS 2048
#define HID 256
#define TSTRIDE 16384  // f16 per time-slot (4 bi-chunks x 4096)

typedef _Float16 half8 __attribute__((ext_vector_type(8)));
typedef float f32x4 __attribute__((ext_vector_type(4)));

// tanh(x) = 1 - 2/(exp2(2*log2e*x)+1): 4 VALU ops. Saturates at +-inf.
__device__ __forceinline__ float tanh_fast(float x){
  float e = __builtin_amdgcn_exp2f(x * 2.8853900817779268f);
  float r = __builtin_amdgcn_rcpf(e + 1.0f);
  return __builtin_fmaf(-2.0f, r, 1.0f);
}

// Load 8 consecutive fp32, round-convert to an MFMA f16x8 fragment.
__device__ __forceinline__ half8 cvt_frag8(const float* __restrict__ p){
  float4 a = *(const float4*)p;
  float4 b = *(const float4*)(p + 4);
  half8 h;
  h[0]=(_Float16)a.x; h[1]=(_Float16)a.y; h[2]=(_Float16)a.z; h[3]=(_Float16)a.w;
  h[4]=(_Float16)b.x; h[5]=(_Float16)b.y; h[6]=(_Float16)b.z; h[7]=(_Float16)b.w;
  return h;
}

// ---------------------------------------------------------------------------
// wcvt: pre-convert Whh0/Wih1/Whh1 to f16 MFMA A-fragments; fused kernel's
// pre-loop load is 48 linear b128 loads per wave. Frag (m, w, mt, kc) at f16
// offset ((m*8+w)*16 + mt*8 + kc)*512 + l*8. Total 384 KB.
// ---------------------------------------------------------------------------
__global__ __launch_bounds__(64) void wcvt(
    const float* __restrict__ W0, const float* __restrict__ W1,
    const float* __restrict__ W2, _Float16* __restrict__ wbuf)
{
  const int m = blockIdx.x >> 3, w = blockIdx.x & 7;
  const int l = threadIdx.x, lm = l & 15, lq = l >> 4;
  const float* W = (m == 0) ? W0 : (m == 1) ? W1 : W2;
  #pragma unroll
  for (int mt = 0; mt < 2; ++mt)
    #pragma unroll
    for (int kc = 0; kc < 8; ++kc){
      half8 f = cvt_frag8(W + (size_t)(w*32 + mt*16 + lm)*HID + kc*32 + lq*8);
      *(half8*)(wbuf + ((size_t)blockIdx.x*16 + mt*8 + kc)*512 + l*8) = f;
    }
}

// ---------------------------------------------------------------------------
// gemm_xp0: xp0[t,b,h] = x[t,b,:]·W_ih0[h,:] + b_ih0[h] + b_hh0[h], f16.
// chunk(t,bi) = xp + (t*4 + bi)*4096 f16. Frag f = w'*64 + l holds acc-layout
// data: element mt*4+r -> hidden w'*32+mt*16+lq*4+r, batch lm.
// ---------------------------------------------------------------------------
__global__ __launch_bounds__(512, 2) void gemm_xp0(
    const float* __restrict__ x, const float* __restrict__ W,
    const float* __restrict__ b1, const float* __restrict__ b2,
    _Float16* __restrict__ xp)
{
  const int t = blockIdx.x, tid = threadIdx.x;
  const int gw = tid >> 6, l = tid & 63;
  const int ng = gw & 1, mg = gw >> 1;
  const int lm = l & 15, lq = l >> 4;

  half8 Af[4][8];
  #pragma unroll
  for (int mt4 = 0; mt4 < 4; ++mt4)
    #pragma unroll
    for (int kc = 0; kc < 8; ++kc)
      Af[mt4][kc] = cvt_frag8(W + (long)(mg*64 + mt4*16 + lm)*HID + kc*32 + lq*8);

  half8 Bf[2][8];
  #pragma unroll
  for (int nt = 0; nt < 2; ++nt)
    #pragma unroll
    for (int kc = 0; kc < 8; ++kc)
      Bf[nt][kc] = cvt_frag8(x + ((long)t*64 + ng*32 + nt*16 + lm)*HID + kc*32 + lq*8);

  f32x4 acc[4][2];
  #pragma unroll
  for (int mt4 = 0; mt4 < 4; ++mt4)
    #pragma unroll
    for (int nt = 0; nt < 2; ++nt)
      acc[mt4][nt] = (f32x4){0.f,0.f,0.f,0.f};

  #pragma unroll
  for (int kc = 0; kc < 8; ++kc)
    #pragma unroll
    for (int mt4 = 0; mt4 < 4; ++mt4)
      #pragma unroll
      for (int nt = 0; nt < 2; ++nt)
        acc[mt4][nt] = __builtin_amdgcn_mfma_f32_16x16x32_f16(
            Af[mt4][kc], Bf[nt][kc], acc[mt4][nt], 0, 0, 0);

  _Float16* chunk0 = xp + ((long)t*4 + ng*2)*4096;
  #pragma unroll
  for (int wp = 0; wp < 2; ++wp){
    const int h0a = mg*64 + (2*wp    )*16 + lq*4;
    const int h0b = mg*64 + (2*wp + 1)*16 + lq*4;
    float4 ba1 = *(const float4*)(b1 + h0a), ba2 = *(const float4*)(b2 + h0a);
    float4 bb1 = *(const float4*)(b1 + h0b), bb2 = *(const float4*)(b2 + h0b);
    #pragma unroll
    for (int nt = 0; nt < 2; ++nt){
      f32x4 v0 = acc[2*wp][nt], v1 = acc[2*wp+1][nt];
      union { _Float16 h[8]; uint4 u; } pk;
      pk.h[0]=(_Float16)(v0[0]+ba1.x+ba2.x); pk.h[1]=(_Float16)(v0[1]+ba1.y+ba2.y);
      pk.h[2]=(_Float16)(v0[2]+ba1.z+ba2.z); pk.h[3]=(_Float16)(v0[3]+ba1.w+ba2.w);
      pk.h[4]=(_Float16)(v1[0]+bb1.x+bb2.x); pk.h[5]=(_Float16)(v1[1]+bb1.y+bb2.y);
      pk.h[6]=(_Float16)(v1[2]+bb1.z+bb2.z); pk.h[7]=(_Float16)(v1[3]+bb1.w+bb2.w);
      *(uint4*)(chunk0 + nt*4096 + ((mg*2 + wp)*64 + l)*8) = pk.u;
    }
  }
}

// ---------------------------------------------------------------------------
// fused_rec: both layers, skewed schedule, one block per 16-batch group.
// Iteration t: h1(t) = tanh(xp0(t) + Whh0·h1(t-1)) AND
//              h2(t-1) = tanh(bias + Wih1·h1(t-1) + Whh1·h2(t-2)),
// one phase, ONE barrier; GEMM0/GEMM1 share B1 -> 16 b128 LDS reads/wave.
// Control flow = round-3 (verified correct). ROUND-5 FIX vs round 3:
// A-fragments pinned to AGPRs via empty-asm "+a" on a V4F32 view (the
// HK-trodden constraint class; round-4's v8f16 "+a" produced NaN —
// suspected bad lowering). The asm def is non-rematerializable, so the RA
// can no longer re-fetch 48 KB/wave of A-frags from L2 every step (round-3
// counters: VGPR_Count=124 -> all 192 frag regs were remat'd; 384 KB/step/CU
// / 128 B/cyc = 3072 cyc = the whole measured step). gfx950 MFMA reads srcA
// directly from AGPR, so no per-use copies.
// Budget: 192 AGPR + ~60 VGPR <= 256/wave at 2 waves/SIMD.
// ---------------------------------------------------------------------------
__global__ __launch_bounds__(512, 2) void fused_rec(
    const _Float16* __restrict__ xp, const _Float16* __restrict__ wbuf,
    const float* __restrict__ b1, const float* __restrict__ b2,
    _Float16* __restrict__ hout)
{
  __shared__ __align__(16) _Float16 h1f[2][8][64][8];
  __shared__ __align__(16) _Float16 h2f[2][8][64][8];
  const int bi = blockIdx.x, tid = threadIdx.x;
  const int w = tid >> 6, l = tid & 63;
  const int lm = l & 15, lq = l >> 4;

  // zero BOTH buffers (t=0 reads [1]; t=1 reads h2f[0] which must be 0)
  for (int i = tid; i < 2*8*64*8; i += 512){
    (&h1f[0][0][0][0])[i] = (_Float16)0.f;
    (&h2f[0][0][0][0])[i] = (_Float16)0.f;
  }

  // register-resident A-fragments: 48 linear b128 loads, pinned to AGPR
  // through a v4f32 bit-cast (SSA-level, no address-taken locals).
  const _Float16* wb = wbuf + (size_t)w*16*512 + (size_t)l*8;
  half8 A0[2][8], A1[2][8], A2[2][8];
  #pragma unroll
  for (int mt = 0; mt < 2; ++mt)
    #pragma unroll
    for (int kc = 0; kc < 8; ++kc){
      half8 v0 = *(const half8*)(wb +      0 + (mt*8 + kc)*512);
      half8 v1 = *(const half8*)(wb +  65536 + (mt*8 + kc)*512);
      half8 v2 = *(const half8*)(wb + 131072 + (mt*8 + kc)*512);
      f32x4 t0 = __builtin_bit_cast(f32x4, v0);
      f32x4 t1 = __builtin_bit_cast(f32x4, v1);
      f32x4 t2 = __builtin_bit_cast(f32x4, v2);
      asm volatile("" : "+a"(t0));
      asm volatile("" : "+a"(t1));
      asm volatile("" : "+a"(t2));
      A0[mt][kc] = __builtin_bit_cast(half8, t0);
      A1[mt][kc] = __builtin_bit_cast(half8, t1);
      A2[mt][kc] = __builtin_bit_cast(half8, t2);
    }

  // layer-2 bias fragments (C-init of GEMM1)
  f32x4 biasf[2];
  #pragma unroll
  for (int mt = 0; mt < 2; ++mt){
    const int h0 = w*32 + mt*16 + lq*4;
    f32x4 b;
    b[0]=b1[h0+0]+b2[h0+0]; b[1]=b1[h0+1]+b2[h0+1];
    b[2]=b1[h0+2]+b2[h0+2]; b[3]=b1[h0+3]+b2[h0+3];
    biasf[mt] = b;
  }
  __syncthreads();

  const _Float16* chunk0 = xp + (size_t)bi*4096;
  uint4 xv = *(const uint4*)(chunk0 + ((size_t)w*64 + l)*8);   // xp0(0)
  _Float16* hob = hout + ((size_t)bi*16 + lm)*HID + w*32 + lq*4;

  for (int t = 0; t <= T_STEPS; ++t){
    const int pb = (t + 1) & 1, cb = t & 1;

    // acc1 init from xp0(t) fragment; acc2 init from bias
    union { uint4 u; _Float16 h[8]; } xa; xa.u = xv;
    f32x4 acc1[2], acc2[2];
    acc1[0][0]=(float)xa.h[0]; acc1[0][1]=(float)xa.h[1]; acc1[0][2]=(float)xa.h[2]; acc1[0][3]=(float)xa.h[3];
    acc1[1][0]=(float)xa.h[4]; acc1[1][1]=(float)xa.h[5]; acc1[1][2]=(float)xa.h[6]; acc1[1][3]=(float)xa.h[7];
    acc2[0] = biasf[0]; acc2[1] = biasf[1];

    // prefetch next step's xp (latency hidden under this step's compute)
    if (t + 1 < T_STEPS)
      xv = *(const uint4*)(chunk0 + (size_t)(t+1)*TSTRIDE + ((size_t)w*64 + l)*8);

    // one phase: GEMM0 (h1 rec) + GEMM1 (shares B1!) + GEMM2 (h2 rec)
    #pragma unroll
    for (int kc = 0; kc < 8; ++kc){
      half8 B1 = *(const half8*)&h1f[pb][kc][l][0];   // h1(t-1)
      half8 B2 = *(const half8*)&h2f[pb][kc][l][0];   // h2(t-2)
      acc1[0] = __builtin_amdgcn_mfma_f32_16x16x32_f16(A0[0][kc], B1, acc1[0], 0,0,0);
      acc1[1] = __builtin_amdgcn_mfma_f32_16x16x32_f16(A0[1][kc], B1, acc1[1], 0,0,0);
      acc2[0] = __builtin_amdgcn_mfma_f32_16x16x32_f16(A1[0][kc], B1, acc2[0], 0,0,0);
      acc2[1] = __builtin_amdgcn_mfma_f32_16x16x32_f16(A1[1][kc], B1, acc2[1], 0,0,0);
      acc2[0] = __builtin_amdgcn_mfma_f32_16x16x32_f16(A2[0][kc], B2, acc2[0], 0,0,0);
      acc2[1] = __builtin_amdgcn_mfma_f32_16x16x32_f16(A2[1][kc], B2, acc2[1], 0,0,0);
    }

    // h1(t) -> LDS B-frag layout (kc = w for a 32-row wave).
    // row k = w*32+mt*16+lq*4+r -> lane lm+16*(2mt+(lq>>1)), elem (lq&1)*4+r.
    if (t < T_STEPS){
      #pragma unroll
      for (int mt = 0; mt < 2; ++mt){
        union { _Float16 h[4]; unsigned long long u; } p;
        p.h[0]=(_Float16)tanh_fast(acc1[mt][0]); p.h[1]=(_Float16)tanh_fast(acc1[mt][1]);
        p.h[2]=(_Float16)tanh_fast(acc1[mt][2]); p.h[3]=(_Float16)tanh_fast(acc1[mt][3]);
        *(unsigned long long*)&h1f[cb][w][lm + 16*(mt*2 + (lq>>1))][(lq&1)*4] = p.u;
      }
    }
    // h2(t-1) -> LDS state + global out
    if (t > 0){
      #pragma unroll
      for (int mt = 0; mt < 2; ++mt){
        union { _Float16 h[4]; unsigned long long u; } q;
        q.h[0]=(_Float16)tanh_fast(acc2[mt][0]); q.h[1]=(_Float16)tanh_fast(acc2[mt][1]);
        q.h[2]=(_Float16)tanh_fast(acc2[mt][2]); q.h[3]=(_Float16)tanh_fast(acc2[mt][3]);
        *(unsigned long long*)&h2f[cb][w][lm + 16*(mt*2 + (lq>>1))][(lq&1)*4] = q.u;
        *(unsigned long long*)(hob + (size_t)(t-1)*64*HID + mt*16) = q.u;
      }
    }
    __syncthreads();
  }
}

// f16 -> fp32 final output, full-device, HBM-bound (~192 MiB moved).
__global__ __launch_bounds__(256) void cvt_out(
    const _Float16* __restrict__ hin, float* __restrict__ out)
{
  const long i = ((long)blockIdx.x*256 + threadIdx.x)*8;
  half8 v = *(const half8*)(hin + i);
  float4 a, b;
  a.x=(float)v[0]; a.y=(float)v[1]; a.z=(float)v[2]; a.w=(float)v[3];
  b.x=(float)v[4]; b.y=(float)v[5]; b.z=(float)v[6]; b.w=(float)v[7];
  *(float4*)(out + i)     = a;
  *(float4*)(out + i + 4) = b;
}

// ---------------------------------------------------------------------------
// Buffers: d_out low 64 MiB = xp0 (f16, dead before cvt_out); d_out + 64 MiB
// = wbuf (384 KB f16 weight frags, dead until cvt_out overwrites at the end).
// h2 f16 (64 MiB) -> d_ws; final fp32 -> d_out (128 MiB).
// ---------------------------------------------------------------------------
extern "C" void kernel_launch(void* const* d_in, const int* in_sizes, int n_in,
                              void* d_out, int out_size, void* d_ws, size_t ws_size,
                              hipStream_t stream)
{
  const float* x     = (const float*)d_in[0];
  const float* W_ih0 = (const float*)d_in[1];
  const float* W_hh0 = (const float*)d_in[2];
  const float* b_ih0 = (const float*)d_in[3];
  const float* b_hh0 = (const float*)d_in[4];
  const float* W_ih1 = (const float*)d_in[5];
  const float* W_hh1 = (const float*)d_in[6];
  const float* b_ih1 = (const float*)d_in[7];
  const float* b_hh1 = (const float*)d_in[8];

  _Float16* xp0  = (_Float16*)d_out;
  _Float16* wbuf = (_Float16*)((char*)d_out + (size_t)T_STEPS*64*HID*2);
  _Float16* h2   = (_Float16*)d_ws;

  wcvt<<<24, 64, 0, stream>>>(W_hh0, W_ih1, W_hh1, wbuf);
  gemm_xp0<<<T_STEPS, 512, 0, stream>>>(x, W_ih0, b_ih0, b_hh0, xp0);
  fused_rec<<<4, 512, 0, stream>>>(xp0, wbuf, b_ih1, b_hh1, h2);
  cvt_out<<<(T_STEPS*64*HID)/(256*8), 256, 0, stream>>>(h2, (float*)d_out);
}